// Round 1
// baseline (206.522 us; speedup 1.0000x reference)
//
#include <hip/hip_runtime.h>

#define Bn 8
#define Xn 2048
#define Yn 2048
#define Hn 1024
#define YCHUNK 64

// K1: sq[row] = dot(q[row,:], Wq), one wave per row, 4 rows per block.
__global__ void k_sq(const float* __restrict__ q, const float* __restrict__ W,
                     float* __restrict__ sq) {
    const float4* w4 = (const float4*)(W + Hn);  // Wq = W[H:]
    int wave = threadIdx.x >> 6;
    int lane = threadIdx.x & 63;
    int row  = blockIdx.x * 4 + wave;            // 0 .. B*Y-1
    const float4* q4 = (const float4*)(q + (size_t)row * Hn);
    float acc = 0.f;
    #pragma unroll
    for (int i = 0; i < 4; ++i) {                // 64 lanes * 4 float4 = 1024 = H
        float4 a = q4[lane + 64 * i];
        float4 b = w4[lane + 64 * i];
        acc += a.x * b.x + a.y * b.y + a.z * b.z + a.w * b.w;
    }
    #pragma unroll
    for (int off = 32; off > 0; off >>= 1)
        acc += __shfl_xor(acc, off, 64);
    if (lane == 0) sq[row] = acc;
}

// K2: per-batch softmax over Y (block=256, 8 vals/thread); also zero o[b,:].
__global__ void k_softmax(const float* __restrict__ sq, float* __restrict__ p,
                          float* __restrict__ o) {
    int b = blockIdx.x;
    int t = threadIdx.x;
    int wave = t >> 6, lane = t & 63;
    __shared__ float wred[4];

    float vals[8];
    float m = -1e30f;
    #pragma unroll
    for (int i = 0; i < 8; ++i) {
        vals[i] = sq[b * Yn + t + 256 * i];
        m = fmaxf(m, vals[i]);
    }
    #pragma unroll
    for (int off = 32; off > 0; off >>= 1)
        m = fmaxf(m, __shfl_xor(m, off, 64));
    if (lane == 0) wred[wave] = m;
    __syncthreads();
    m = fmaxf(fmaxf(wred[0], wred[1]), fmaxf(wred[2], wred[3]));
    __syncthreads();

    float s = 0.f;
    #pragma unroll
    for (int i = 0; i < 8; ++i) { vals[i] = __expf(vals[i] - m); s += vals[i]; }
    #pragma unroll
    for (int off = 32; off > 0; off >>= 1)
        s += __shfl_xor(s, off, 64);
    if (lane == 0) wred[wave] = s;
    __syncthreads();
    s = wred[0] + wred[1] + wred[2] + wred[3];
    float inv = 1.f / s;
    #pragma unroll
    for (int i = 0; i < 8; ++i) p[b * Yn + t + 256 * i] = vals[i] * inv;

    // zero the o accumulator (ws is poisoned 0xAA every launch)
    #pragma unroll
    for (int i = 0; i < 4; ++i) o[b * Hn + t + 256 * i] = 0.f;
}

// K3: o[b,h] += sum_{y in chunk} p[b,y] * v[b,y,h]; one float4 column per thread.
__global__ void k_pv(const float* __restrict__ v, const float* __restrict__ p,
                     float* __restrict__ o) {
    int b = blockIdx.y;
    int y0 = blockIdx.x * YCHUNK;
    int h4 = threadIdx.x;                        // 0..255 = H/4
    const float4* v4 = (const float4*)(v + (size_t)b * Yn * Hn);
    float4 acc = {0.f, 0.f, 0.f, 0.f};
    for (int yy = 0; yy < YCHUNK; ++yy) {
        float pw = p[b * Yn + y0 + yy];
        float4 vv = v4[(size_t)(y0 + yy) * (Hn / 4) + h4];
        acc.x += pw * vv.x; acc.y += pw * vv.y;
        acc.z += pw * vv.z; acc.w += pw * vv.w;
    }
    float* ob = o + b * Hn + 4 * h4;
    atomicAdd(ob + 0, acc.x);
    atomicAdd(ob + 1, acc.y);
    atomicAdd(ob + 2, acc.z);
    atomicAdd(ob + 3, acc.w);
}

// K4: out[b,x,h] = o[b,h] broadcast; float4 stores, o stays L2-resident.
__global__ void k_bcast(const float* __restrict__ o, float4* __restrict__ out) {
    size_t i = (size_t)blockIdx.x * blockDim.x + threadIdx.x;  // over B*X*H/4
    int h4 = (int)(i & (Hn / 4 - 1));
    size_t row = i >> 8;                          // b*X + x
    int b = (int)(row >> 11);                     // X = 2048
    const float4* o4 = (const float4*)o;
    out[i] = o4[b * (Hn / 4) + h4];
}

extern "C" void kernel_launch(void* const* d_in, const int* in_sizes, int n_in,
                              void* d_out, int out_size, void* d_ws, size_t ws_size,
                              hipStream_t stream) {
    const float* q = (const float*)d_in[0];
    // d_in[1] = k : provably unused (cancels in softmax over y)
    const float* v = (const float*)d_in[2];
    const float* W = (const float*)d_in[3];
    // d_in[4] = b : scalar, also cancels
    float* out = (float*)d_out;

    float* sq = (float*)d_ws;          // B*Y floats  (64 KB)
    float* p  = sq + Bn * Yn;          // B*Y floats  (64 KB)
    float* o  = p  + Bn * Yn;          // B*H floats  (32 KB)

    k_sq     <<<Bn * Yn / 4, 256, 0, stream>>>(q, W, sq);
    k_softmax<<<Bn, 256, 0, stream>>>(sq, p, o);
    k_pv     <<<dim3(Yn / YCHUNK, Bn), 256, 0, stream>>>(v, p, o);
    k_bcast  <<<(Bn * (size_t)Xn * Hn / 4) / 256, 256, 0, stream>>>(o, (float4*)out);
}